// Round 3
// baseline (1806.095 us; speedup 1.0000x reference)
//
#include <hip/hip_runtime.h>
#include <hip/hip_bf16.h>
#include <math.h>

#define D 128

// Tree-reduce R rows of 128 floats each in LDS; after return red[r*D+0] = row sum.
template<int R>
__device__ __forceinline__ void multiReduce(float* red, int j){
    __syncthreads();
    #pragma unroll
    for (int s = 64; s > 0; s >>= 1){
        if (j < s){
            #pragma unroll
            for (int r = 0; r < R; ++r) red[r*D + j] += red[r*D + j + s];
        }
        __syncthreads();
    }
}

// acc[r] = bias[j] + sum_i sh[r*D+i] * W[i*D+j]   (W is f32, row-major DxD)
template<int R>
__device__ __forceinline__ void matvec(const float* sh, const float* __restrict__ W,
                                       const float* __restrict__ bias, int j, float* acc){
    float bb = bias[j];
    #pragma unroll
    for (int r = 0; r < R; ++r) acc[r] = bb;
    #pragma unroll 8
    for (int i = 0; i < D; ++i){
        float w = W[i*D + j];
        #pragma unroll
        for (int r = 0; r < R; ++r) acc[r] += sh[r*D + i] * w;
    }
}

__device__ __forceinline__ float gelu_exact(float x){
    return 0.5f * x * (1.0f + erff(x * 0.70710678118654752f));
}

// Fused pre-LN transformer block (q/k dead: softmax over size-1 axis == 1, ctx == v).
template<int R>
__global__ __launch_bounds__(128)
void k_dense(const float* __restrict__ ent,
             const float* __restrict__ g1, const float* __restrict__ be1,
             const float* __restrict__ wv, const float* __restrict__ bv,
             const float* __restrict__ wo, const float* __restrict__ bo,
             const float* __restrict__ g2, const float* __restrict__ be2,
             const float* __restrict__ w1, const float* __restrict__ b1,
             const float* __restrict__ w2, const float* __restrict__ b2,
             float* __restrict__ gcn_in, int n)
{
    const int j = threadIdx.x;
    const int row0 = blockIdx.x * R;
    __shared__ float sh[R*D];
    __shared__ float red[R*D];

    float e[R];
    #pragma unroll
    for (int r = 0; r < R; ++r){
        int rr = row0 + r;
        e[r] = (rr < n) ? ent[(size_t)rr * D + j] : 0.0f;
    }

    // ---- LN1 ----
    #pragma unroll
    for (int r = 0; r < R; ++r) red[r*D + j] = e[r];
    multiReduce<R>(red, j);
    float mu[R];
    #pragma unroll
    for (int r = 0; r < R; ++r) mu[r] = red[r*D] * (1.0f/D);
    __syncthreads();
    #pragma unroll
    for (int r = 0; r < R; ++r){ float d = e[r]-mu[r]; red[r*D + j] = d*d; }
    multiReduce<R>(red, j);
    float g1v = g1[j], b1v = be1[j];
    #pragma unroll
    for (int r = 0; r < R; ++r){
        float rs = rsqrtf(red[r*D] * (1.0f/D) + 1e-5f);
        sh[r*D + j] = (e[r]-mu[r]) * rs * g1v + b1v;
    }
    __syncthreads();

    // ---- v = y@wv+bv ; ctx == v (softmax over length-1 seq == 1) ----
    float v[R]; matvec<R>(sh, wv, bv, j, v);
    __syncthreads();
    #pragma unroll
    for (int r = 0; r < R; ++r) sh[r*D + j] = v[r];
    __syncthreads();

    // ---- x = e + v@wo + bo ----
    float x[R]; matvec<R>(sh, wo, bo, j, x);
    #pragma unroll
    for (int r = 0; r < R; ++r) x[r] += e[r];

    // ---- LN2 ----
    #pragma unroll
    for (int r = 0; r < R; ++r) red[r*D + j] = x[r];
    multiReduce<R>(red, j);
    #pragma unroll
    for (int r = 0; r < R; ++r) mu[r] = red[r*D] * (1.0f/D);
    __syncthreads();
    #pragma unroll
    for (int r = 0; r < R; ++r){ float d = x[r]-mu[r]; red[r*D + j] = d*d; }
    multiReduce<R>(red, j);
    float g2v = g2[j], b2v = be2[j];
    #pragma unroll
    for (int r = 0; r < R; ++r){
        float rs = rsqrtf(red[r*D] * (1.0f/D) + 1e-5f);
        sh[r*D + j] = (x[r]-mu[r]) * rs * g2v + b2v;
    }
    __syncthreads();

    // ---- h = gelu(y2@w1+b1) ----
    float h[R]; matvec<R>(sh, w1, b1, j, h);
    __syncthreads();
    #pragma unroll
    for (int r = 0; r < R; ++r) sh[r*D + j] = gelu_exact(h[r]);
    __syncthreads();

    // ---- gcn_in = x + h@w2 + b2 ----
    float o[R]; matvec<R>(sh, w2, b2, j, o);
    #pragma unroll
    for (int r = 0; r < R; ++r){
        int rr = row0 + r;
        if (rr < n) gcn_in[(size_t)rr * D + j] = x[r] + o[r];
    }
}

__global__ __launch_bounds__(256)
void k_gcn_scatter(const int* __restrict__ eidx, const float* __restrict__ ew,
                   const float* __restrict__ gcn_in,
                   float* __restrict__ neigh, float* __restrict__ rowsum, int E)
{
    long long t = (long long)blockIdx.x * blockDim.x + threadIdx.x;
    int e = (int)(t >> 7), j = (int)(t & 127);
    if (e >= E) return;
    int r = eidx[e], c = eidx[E + e];
    float w = ew[e];
    atomicAdd(&neigh[(size_t)r*D + j], w * gcn_in[(size_t)c*D + j]);
    if (j == 0) atomicAdd(&rowsum[r], w);
}

// GCN normalize -> gat_in = gcn_out@gat_w + gat_b (overwrites neigh buffer; row-disjoint,
// invalid rows read zeros so no cross-block alias)
// also dl[r] = gat_in[r]·watt[:D], dr[r] = gat_in[r]·watt[D:]
template<int R>
__global__ __launch_bounds__(128)
void k_gcn_fin(const float* __restrict__ gcn_in, const float* neigh,
               const float* __restrict__ rowsum,
               const float* __restrict__ lmbda,
               const float* __restrict__ gat_w, const float* __restrict__ gat_b,
               const float* __restrict__ watt,
               float* gat_in, float* __restrict__ dl, float* __restrict__ dr, int n)
{
    const int j = threadIdx.x;
    const int row0 = blockIdx.x * R;
    __shared__ float sh[R*D];
    __shared__ float red[R*D];
    float l1 = lmbda[0], l2 = lmbda[1];

    #pragma unroll
    for (int r = 0; r < R; ++r){
        int rr = row0 + r;
        if (rr < n){
            size_t idx = (size_t)rr * D + j;
            float inv = 1.0f / (1.0f + l2 * rowsum[rr]);
            sh[r*D + j] = (gcn_in[idx] + l2 * neigh[idx]) * inv * l1;
        } else {
            sh[r*D + j] = 0.0f;
        }
    }
    __syncthreads();

    float gv[R]; matvec<R>(sh, gat_w, gat_b, j, gv);
    #pragma unroll
    for (int r = 0; r < R; ++r){
        int rr = row0 + r;
        if (rr < n) gat_in[(size_t)rr * D + j] = gv[r];
    }

    float wl = watt[j], wr = watt[D + j];
    __syncthreads();
    #pragma unroll
    for (int r = 0; r < R; ++r) red[r*D + j] = gv[r] * wl;
    multiReduce<R>(red, j);
    if (j == 0){
        #pragma unroll
        for (int r = 0; r < R; ++r){ int rr = row0 + r; if (rr < n) dl[rr] = red[r*D]; }
    }
    __syncthreads();
    #pragma unroll
    for (int r = 0; r < R; ++r) red[r*D + j] = gv[r] * wr;
    multiReduce<R>(red, j);
    if (j == 0){
        #pragma unroll
        for (int r = 0; r < R; ++r){ int rr = row0 + r; if (rr < n) dr[rr] = red[r*D]; }
    }
}

__global__ __launch_bounds__(256)
void k_gat_scatter(const int* __restrict__ beidx, const int* __restrict__ bids,
                   const float* __restrict__ dl, const float* __restrict__ dr,
                   const float* __restrict__ gat_in,
                   float* __restrict__ e_out, float* __restrict__ e_rowsum, int E2)
{
    long long t = (long long)blockIdx.x * blockDim.x + threadIdx.x;
    int e = (int)(t >> 7), j = (int)(t & 127);
    if (e >= E2) return;
    int br = beidx[e], bc = beidx[E2 + e];
    float ev = dl[bids[br]] + dr[bc];
    float lr = ev > 0.0f ? ev : 0.2f * ev;
    float att = expf(-lr);
    atomicAdd(&e_out[(size_t)br*D + j], att * gat_in[(size_t)bc*D + j]);
    if (j == 0) atomicAdd(&e_rowsum[br], att);
}

__global__ __launch_bounds__(256)
void k_final(const float* __restrict__ e_out, const float* __restrict__ e_rowsum,
             const float* __restrict__ prelu_a, float* __restrict__ out, int total)
{
    int t = blockIdx.x * blockDim.x + threadIdx.x;
    if (t >= total) return;
    float pa = prelu_a[0];
    float v = e_out[t] / e_rowsum[t >> 7];
    out[t] = v > 0.0f ? v : pa * v;   // PReLU, f32 output
}

extern "C" void kernel_launch(void* const* d_in, const int* in_sizes, int n_in,
                              void* d_out, int out_size, void* d_ws, size_t ws_size,
                              hipStream_t stream)
{
    const float* ent   = (const float*)d_in[0];
    const float* ew    = (const float*)d_in[1];
    const float* ln1_g = (const float*)d_in[2];
    const float* ln1_b = (const float*)d_in[3];
    // d_in[4..7] = wq,bq,wk,bk : dead (softmax over size-1 axis == 1 -> ctx == v)
    const float* wv    = (const float*)d_in[8];
    const float* bv    = (const float*)d_in[9];
    const float* wo    = (const float*)d_in[10];
    const float* bo    = (const float*)d_in[11];
    const float* ln2_g = (const float*)d_in[12];
    const float* ln2_b = (const float*)d_in[13];
    const float* w1    = (const float*)d_in[14];
    const float* b1    = (const float*)d_in[15];
    const float* w2    = (const float*)d_in[16];
    const float* b2    = (const float*)d_in[17];
    const float* lmbda = (const float*)d_in[18];
    const float* gat_w = (const float*)d_in[19];
    const float* gat_b = (const float*)d_in[20];
    const float* watt  = (const float*)d_in[21];
    const float* prelu = (const float*)d_in[22];
    const int* eidx    = (const int*)d_in[23];
    const int* bids    = (const int*)d_in[24];
    const int* beidx   = (const int*)d_in[25];

    const int n  = in_sizes[24];        // N entities
    const int E  = in_sizes[1];         // KG edges
    const int E2 = in_sizes[25] / 2;    // batch edges (E + N self loops)

    char* ws = (char*)d_ws;
    const size_t szND = (size_t)n * D * sizeof(float);
    float* bufA     = (float*)ws;                       // gcn_in, later e_out
    float* bufB     = (float*)(ws + szND);              // neigh_sum, later gat_in
    float* rowsum   = (float*)(ws + 2*szND);            // [n]
    float* e_rowsum = rowsum + n;                       // [n]
    float* dl       = e_rowsum + n;                     // [n]
    float* dr       = dl + n;                           // [n]

    constexpr int R = 4;
    const int nblk = (n + R - 1) / R;

    k_dense<R><<<nblk, 128, 0, stream>>>(ent, ln1_g, ln1_b, wv, bv, wo, bo,
                                         ln2_g, ln2_b, w1, b1, w2, b2, bufA, n);

    hipMemsetAsync(bufB, 0, szND + (size_t)n*sizeof(float), stream);  // neigh + rowsum
    k_gcn_scatter<<<(int)(((long long)E*D + 255)/256), 256, 0, stream>>>(
        eidx, ew, bufA, bufB, rowsum, E);

    k_gcn_fin<R><<<nblk, 128, 0, stream>>>(bufA, bufB, rowsum, lmbda,
                                           gat_w, gat_b, watt, bufB, dl, dr, n);

    hipMemsetAsync(bufA, 0, szND, stream);                 // e_out
    hipMemsetAsync(e_rowsum, 0, (size_t)n*sizeof(float), stream);
    k_gat_scatter<<<(int)(((long long)E2*D + 255)/256), 256, 0, stream>>>(
        beidx, bids, dl, dr, bufB, bufA, e_rowsum, E2);

    k_final<<<(int)(((size_t)n*D + 255)/256), 256, 0, stream>>>(
        bufA, e_rowsum, prelu, (float*)d_out, n*D);
}

// Round 4
// 1076.142 us; speedup vs baseline: 1.6783x; 1.6783x over previous
//
#include <hip/hip_runtime.h>
#include <hip/hip_bf16.h>
#include <math.h>

#define D 128

// ---------------- LDS helpers ----------------

template<int R>
__device__ __forceinline__ void multiReduce(float* red, int j){
    __syncthreads();
    #pragma unroll
    for (int s = 64; s > 0; s >>= 1){
        if (j < s){
            #pragma unroll
            for (int r = 0; r < R; ++r) red[r*D + j] += red[r*D + j + s];
        }
        __syncthreads();
    }
}

// acc[r] = bias[j] + sum_i sh[r*D+i] * W[i*D+j]   (W f32 row-major DxD)
template<int R>
__device__ __forceinline__ void matvec(const float* sh, const float* __restrict__ W,
                                       const float* __restrict__ bias, int j, float* acc){
    float bb = bias[j];
    #pragma unroll
    for (int r = 0; r < R; ++r) acc[r] = bb;
    #pragma unroll 8
    for (int i = 0; i < D; ++i){
        float w = W[i*D + j];
        #pragma unroll
        for (int r = 0; r < R; ++r) acc[r] += sh[r*D + i] * w;
    }
}

__device__ __forceinline__ float gelu_exact(float x){
    return 0.5f * x * (1.0f + erff(x * 0.70710678118654752f));
}

// ---------------- dense transformer block (unchanged) ----------------
// q/k dead: softmax over size-1 axis == 1 -> ctx == v.
template<int R>
__global__ __launch_bounds__(128)
void k_dense(const float* __restrict__ ent,
             const float* __restrict__ g1, const float* __restrict__ be1,
             const float* __restrict__ wv, const float* __restrict__ bv,
             const float* __restrict__ wo, const float* __restrict__ bo,
             const float* __restrict__ g2, const float* __restrict__ be2,
             const float* __restrict__ w1, const float* __restrict__ b1,
             const float* __restrict__ w2, const float* __restrict__ b2,
             float* __restrict__ gcn_in, int n)
{
    const int j = threadIdx.x;
    const int row0 = blockIdx.x * R;
    __shared__ float sh[R*D];
    __shared__ float red[R*D];

    float e[R];
    #pragma unroll
    for (int r = 0; r < R; ++r){
        int rr = row0 + r;
        e[r] = (rr < n) ? ent[(size_t)rr * D + j] : 0.0f;
    }

    // LN1
    #pragma unroll
    for (int r = 0; r < R; ++r) red[r*D + j] = e[r];
    multiReduce<R>(red, j);
    float mu[R];
    #pragma unroll
    for (int r = 0; r < R; ++r) mu[r] = red[r*D] * (1.0f/D);
    __syncthreads();
    #pragma unroll
    for (int r = 0; r < R; ++r){ float d = e[r]-mu[r]; red[r*D + j] = d*d; }
    multiReduce<R>(red, j);
    float g1v = g1[j], b1v = be1[j];
    #pragma unroll
    for (int r = 0; r < R; ++r){
        float rs = rsqrtf(red[r*D] * (1.0f/D) + 1e-5f);
        sh[r*D + j] = (e[r]-mu[r]) * rs * g1v + b1v;
    }
    __syncthreads();

    // v = y@wv+bv ; ctx == v
    float v[R]; matvec<R>(sh, wv, bv, j, v);
    __syncthreads();
    #pragma unroll
    for (int r = 0; r < R; ++r) sh[r*D + j] = v[r];
    __syncthreads();

    // x = e + v@wo + bo
    float x[R]; matvec<R>(sh, wo, bo, j, x);
    #pragma unroll
    for (int r = 0; r < R; ++r) x[r] += e[r];

    // LN2
    #pragma unroll
    for (int r = 0; r < R; ++r) red[r*D + j] = x[r];
    multiReduce<R>(red, j);
    #pragma unroll
    for (int r = 0; r < R; ++r) mu[r] = red[r*D] * (1.0f/D);
    __syncthreads();
    #pragma unroll
    for (int r = 0; r < R; ++r){ float d = x[r]-mu[r]; red[r*D + j] = d*d; }
    multiReduce<R>(red, j);
    float g2v = g2[j], b2v = be2[j];
    #pragma unroll
    for (int r = 0; r < R; ++r){
        float rs = rsqrtf(red[r*D] * (1.0f/D) + 1e-5f);
        sh[r*D + j] = (x[r]-mu[r]) * rs * g2v + b2v;
    }
    __syncthreads();

    // h = gelu(y2@w1+b1)
    float h[R]; matvec<R>(sh, w1, b1, j, h);
    __syncthreads();
    #pragma unroll
    for (int r = 0; r < R; ++r) sh[r*D + j] = gelu_exact(h[r]);
    __syncthreads();

    // gcn_in = x + h@w2 + b2
    float o[R]; matvec<R>(sh, w2, b2, j, o);
    #pragma unroll
    for (int r = 0; r < R; ++r){
        int rr = row0 + r;
        if (rr < n) gcn_in[(size_t)rr * D + j] = x[r] + o[r];
    }
}

// ---------------- device CSR build ----------------

__global__ __launch_bounds__(256)
void k_hist(const int* __restrict__ rows, int* __restrict__ deg, int E){
    int i = blockIdx.x * 256 + threadIdx.x;
    if (i < E) atomicAdd(&deg[rows[i]], 1);
}

// block partial sums of deg (256 elems per block)
__global__ __launch_bounds__(256)
void k_scan_partial(const int* __restrict__ deg, int* __restrict__ bsum, int n){
    __shared__ int s[256];
    int i = blockIdx.x * 256 + threadIdx.x;
    s[threadIdx.x] = (i < n) ? deg[i] : 0;
    __syncthreads();
    #pragma unroll
    for (int st = 128; st > 0; st >>= 1){
        if (threadIdx.x < st) s[threadIdx.x] += s[threadIdx.x + st];
        __syncthreads();
    }
    if (threadIdx.x == 0) bsum[blockIdx.x] = s[0];
}

// single-block exclusive scan of block sums (nb <= 1024, i.e. n <= 262144)
__global__ __launch_bounds__(1024)
void k_scan_bsums(int* __restrict__ bsum, int nb){
    __shared__ int a[1024], b[1024];
    int t = threadIdx.x;
    int orig = (t < nb) ? bsum[t] : 0;
    int *src = a, *dst = b;
    src[t] = orig;
    __syncthreads();
    for (int off = 1; off < 1024; off <<= 1){
        dst[t] = src[t] + ((t >= off) ? src[t-off] : 0);
        __syncthreads();
        int* tmp = src; src = dst; dst = tmp;
    }
    if (t < nb) bsum[t] = src[t] - orig;   // exclusive
}

// final exclusive scan: start[i] (and cursor copy); start[n] = total
__global__ __launch_bounds__(256)
void k_scan_final(const int* __restrict__ deg, const int* __restrict__ bsum,
                  int* __restrict__ start, int* __restrict__ cur, int n, int total){
    __shared__ int a[256], b[256];
    int t = threadIdx.x;
    int i = blockIdx.x * 256 + t;
    int orig = (i < n) ? deg[i] : 0;
    int *src = a, *dst = b;
    src[t] = orig;
    __syncthreads();
    for (int off = 1; off < 256; off <<= 1){
        dst[t] = src[t] + ((t >= off) ? src[t-off] : 0);
        __syncthreads();
        int* tmp = src; src = dst; dst = tmp;
    }
    int excl = src[t] - orig + bsum[blockIdx.x];
    if (i < n){ start[i] = excl; cur[i] = excl; }
    if (i == n-1) start[n] = total;
}

__global__ __launch_bounds__(256)
void k_fill_gcn(const int* __restrict__ eidx, const float* __restrict__ ew,
                int* __restrict__ cur, int* __restrict__ colp, float* __restrict__ wp, int E){
    int i = blockIdx.x * 256 + threadIdx.x;
    if (i < E){
        int r = eidx[i];
        int pos = atomicAdd(&cur[r], 1);
        colp[pos] = eidx[E + i];
        wp[pos]   = ew[i];
    }
}

__global__ __launch_bounds__(256)
void k_fill_gat(const int* __restrict__ beidx, int* __restrict__ cur,
                int* __restrict__ colp, int E2){
    int i = blockIdx.x * 256 + threadIdx.x;
    if (i < E2){
        int r = beidx[i];
        int pos = atomicAdd(&cur[r], 1);
        colp[pos] = beidx[E2 + i];
    }
}

// ---------------- GCN pull + normalize + gat_w matvec + attention scalars ----------------
template<int R>
__global__ __launch_bounds__(128)
void k_gcn_pull_fin(const float* __restrict__ gcn_in,
                    const int* __restrict__ start, const int* __restrict__ colp,
                    const float* __restrict__ wp,
                    const float* __restrict__ lmbda,
                    const float* __restrict__ gat_w, const float* __restrict__ gat_b,
                    const float* __restrict__ watt,
                    float* __restrict__ gat_in,
                    float* __restrict__ dl, float* __restrict__ dr, int n)
{
    const int j = threadIdx.x;
    const int row0 = blockIdx.x * R;
    __shared__ float sh[R*D];
    __shared__ float red[R*D];
    float l1 = lmbda[0], l2 = lmbda[1];

    #pragma unroll
    for (int r = 0; r < R; ++r){
        int rr = row0 + r;
        if (rr < n){
            float acc = 0.0f, wsum = 0.0f;
            int s0 = start[rr], s1 = start[rr+1];
            for (int e = s0; e < s1; ++e){
                int   c = colp[e];
                float w = wp[e];
                acc  += w * gcn_in[(size_t)c * D + j];
                wsum += w;
            }
            float base = gcn_in[(size_t)rr * D + j];
            sh[r*D + j] = (base + l2 * acc) / (1.0f + l2 * wsum) * l1;
        } else {
            sh[r*D + j] = 0.0f;
        }
    }
    __syncthreads();

    float gv[R]; matvec<R>(sh, gat_w, gat_b, j, gv);
    #pragma unroll
    for (int r = 0; r < R; ++r){
        int rr = row0 + r;
        if (rr < n) gat_in[(size_t)rr * D + j] = gv[r];
    }

    float wl = watt[j], wr = watt[D + j];
    __syncthreads();
    #pragma unroll
    for (int r = 0; r < R; ++r) red[r*D + j] = gv[r] * wl;
    multiReduce<R>(red, j);
    if (j == 0){
        #pragma unroll
        for (int r = 0; r < R; ++r){ int rr = row0 + r; if (rr < n) dl[rr] = red[r*D]; }
    }
    __syncthreads();
    #pragma unroll
    for (int r = 0; r < R; ++r) red[r*D + j] = gv[r] * wr;
    multiReduce<R>(red, j);
    if (j == 0){
        #pragma unroll
        for (int r = 0; r < R; ++r){ int rr = row0 + r; if (rr < n) dr[rr] = red[r*D]; }
    }
}

// ---------------- GAT pull + normalize + PReLU -> out ----------------
template<int R>
__global__ __launch_bounds__(128)
void k_gat_out(const float* __restrict__ gat_in,
               const int* __restrict__ start2, const int* __restrict__ colp2,
               const int* __restrict__ bids,
               const float* __restrict__ dl, const float* __restrict__ dr,
               const float* __restrict__ prelu_a,
               float* __restrict__ out, int n)
{
    const int j = threadIdx.x;
    const int row0 = blockIdx.x * R;
    float pa = prelu_a[0];

    #pragma unroll
    for (int r = 0; r < R; ++r){
        int rr = row0 + r;
        if (rr < n){
            float dlv = dl[bids[rr]];
            int s0 = start2[rr], s1 = start2[rr+1];
            float acc = 0.0f, es = 0.0f;
            for (int e = s0; e < s1; ++e){
                int c = colp2[e];
                float ev = dlv + dr[c];
                float lr = ev > 0.0f ? ev : 0.2f * ev;
                float att = __expf(-lr);
                es  += att;
                acc += att * gat_in[(size_t)c * D + j];
            }
            float v = acc / es;   // every GAT row has its self-loop -> es > 0
            out[(size_t)rr * D + j] = v > 0.0f ? v : pa * v;
        }
    }
}

// ---------------- launch ----------------

extern "C" void kernel_launch(void* const* d_in, const int* in_sizes, int n_in,
                              void* d_out, int out_size, void* d_ws, size_t ws_size,
                              hipStream_t stream)
{
    const float* ent   = (const float*)d_in[0];
    const float* ew    = (const float*)d_in[1];
    const float* ln1_g = (const float*)d_in[2];
    const float* ln1_b = (const float*)d_in[3];
    // d_in[4..7] = wq,bq,wk,bk : dead (softmax over size-1 axis == 1 -> ctx == v)
    const float* wv    = (const float*)d_in[8];
    const float* bv    = (const float*)d_in[9];
    const float* wo    = (const float*)d_in[10];
    const float* bo    = (const float*)d_in[11];
    const float* ln2_g = (const float*)d_in[12];
    const float* ln2_b = (const float*)d_in[13];
    const float* w1    = (const float*)d_in[14];
    const float* b1    = (const float*)d_in[15];
    const float* w2    = (const float*)d_in[16];
    const float* b2    = (const float*)d_in[17];
    const float* lmbda = (const float*)d_in[18];
    const float* gat_w = (const float*)d_in[19];
    const float* gat_b = (const float*)d_in[20];
    const float* watt  = (const float*)d_in[21];
    const float* prelu = (const float*)d_in[22];
    const int* eidx    = (const int*)d_in[23];
    const int* bids    = (const int*)d_in[24];
    const int* beidx   = (const int*)d_in[25];

    const int n  = in_sizes[24];        // N entities
    const int E  = in_sizes[1];         // KG edges
    const int E2 = in_sizes[25] / 2;    // batch edges (E + N self loops)

    char* ws = (char*)d_ws;
    const size_t szND = (size_t)n * D * sizeof(float);
    size_t off = 0;
    float* bufA   = (float*)(ws + off); off += szND;                    // gcn_in
    float* bufB   = (float*)(ws + off); off += szND;                    // gat_in
    float* dl     = (float*)(ws + off); off += (size_t)n * 4;
    float* dr     = (float*)(ws + off); off += (size_t)n * 4;
    int*   deg1   = (int*)(ws + off);   off += (size_t)n * 4;           // deg1+deg2 adjacent
    int*   deg2   = (int*)(ws + off);   off += (size_t)n * 4;           //  -> single memset
    int*   start1 = (int*)(ws + off);   off += (size_t)(n+1) * 4;
    int*   start2 = (int*)(ws + off);   off += (size_t)(n+1) * 4;
    int*   cur1   = (int*)(ws + off);   off += (size_t)n * 4;
    int*   cur2   = (int*)(ws + off);   off += (size_t)n * 4;
    int*   bsum   = (int*)(ws + off);   off += 1024 * 4;
    int*   colp1  = (int*)(ws + off);   off += (size_t)E * 4;
    float* wp1    = (float*)(ws + off); off += (size_t)E * 4;
    int*   colp2  = (int*)(ws + off);   off += (size_t)E2 * 4;

    constexpr int R = 4;
    const int nblk  = (n + R - 1) / R;
    const int nscan = (n + 255) / 256;

    // dense block
    k_dense<R><<<nblk, 128, 0, stream>>>(ent, ln1_g, ln1_b, wv, bv, wo, bo,
                                         ln2_g, ln2_b, w1, b1, w2, b2, bufA, n);

    // CSR build (both edge sets)
    hipMemsetAsync(deg1, 0, (size_t)2 * n * 4, stream);
    k_hist<<<(E + 255)/256, 256, 0, stream>>>(eidx, deg1, E);
    k_hist<<<(E2 + 255)/256, 256, 0, stream>>>(beidx, deg2, E2);

    k_scan_partial<<<nscan, 256, 0, stream>>>(deg1, bsum, n);
    k_scan_bsums<<<1, 1024, 0, stream>>>(bsum, nscan);
    k_scan_final<<<nscan, 256, 0, stream>>>(deg1, bsum, start1, cur1, n, E);
    k_fill_gcn<<<(E + 255)/256, 256, 0, stream>>>(eidx, ew, cur1, colp1, wp1, E);

    k_scan_partial<<<nscan, 256, 0, stream>>>(deg2, bsum, n);
    k_scan_bsums<<<1, 1024, 0, stream>>>(bsum, nscan);
    k_scan_final<<<nscan, 256, 0, stream>>>(deg2, bsum, start2, cur2, n, E2);
    k_fill_gat<<<(E2 + 255)/256, 256, 0, stream>>>(beidx, cur2, colp2, E2);

    // GCN pull (+ gat_w matvec + attention scalars), no atomics
    k_gcn_pull_fin<R><<<nblk, 128, 0, stream>>>(bufA, start1, colp1, wp1, lmbda,
                                                gat_w, gat_b, watt, bufB, dl, dr, n);

    // GAT pull + PReLU -> out, no atomics
    k_gat_out<R><<<nblk, 128, 0, stream>>>(bufB, start2, colp2, bids, dl, dr,
                                           prelu, (float*)d_out, n);
}